// Round 6
// baseline (1339.984 us; speedup 1.0000x reference)
//
#include <hip/hip_runtime.h>

#define N_NODES 200000
#define N_EDGES 6400000
#define HID 128
#define OUTF 16
#define LAYERS 3
#define EPS 1e-5f

#define NRANGES 16
#define RANGE_N 12500                 // nodes per range
#define NBUCKETS 800
#define BUCKET_N 250                  // nodes per bucket
#define BATCH 5000                    // edges per sort batch
#define NBATCH (N_EDGES / BATCH)      // 1280
#define RCAP 405000                   // range segment capacity (mean 400000, sigma ~612)
#define RBLK (RCAP / BATCH)           // 81 P2 blocks per range
#define BCAP 9500                     // bucket segment capacity (mean 8000, sigma ~89)

#define FTILE 32                      // fused-layer tile rows

typedef unsigned int u32;

__device__ __forceinline__ unsigned short f2bf(float f){
  unsigned int u = __float_as_uint(f);
  u += 0x7fffu + ((u >> 16) & 1u);   // RNE
  return (unsigned short)(u >> 16);
}
__device__ __forceinline__ u32 pack2bf(float lo, float hi){
  return (u32)f2bf(lo) | ((u32)f2bf(hi) << 16);
}

// ---------------- cursor init ----------------

__global__ __launch_bounds__(256) void k_initcur(int* __restrict__ range_cursor,
                                                 int* __restrict__ bucket_cursor){
  int t = blockIdx.x * 256 + threadIdx.x;
  if (t < NRANGES) range_cursor[t] = t * RCAP;
  if (t < NBUCKETS) bucket_cursor[t] = t * BCAP;
}

// ---------------- P1: batch-sort edges into 16 dst ranges (full-line flushes) ----------------
// entry = (dst_local_in_range:14 | src:18); range implicit by segment.

__global__ __launch_bounds__(256) void k_p1(const int* __restrict__ src, const int* __restrict__ dst,
                                            int* __restrict__ range_cursor, u32* __restrict__ ebuf1){
  __shared__ u32 stage[BATCH];
  __shared__ int hist[NRANGES], hist2[NRANGES], hbase[NRANGES], gbase[NRANGES];
  const int tid = threadIdx.x;
  const long e0 = (long)blockIdx.x * BATCH;

  if (tid < NRANGES){ hist[tid] = 0; hist2[tid] = 0; }
  __syncthreads();
  for (int i = tid; i < BATCH; i += 256){
    int d = dst[e0 + i];
    atomicAdd(&hist[d / RANGE_N], 1);
  }
  __syncthreads();
  if (tid == 0){ int run = 0; for (int b = 0; b < NRANGES; b++){ hbase[b] = run; run += hist[b]; } }
  __syncthreads();
  if (tid < NRANGES && hist[tid] > 0) gbase[tid] = atomicAdd(&range_cursor[tid], hist[tid]);
  __syncthreads();
  for (int i = tid; i < BATCH; i += 256){
    int d = dst[e0 + i];
    int s = src[e0 + i];
    int r = d / RANGE_N;
    u32 pk = ((u32)(d - r * RANGE_N) << 18) | (u32)s;
    int p = atomicAdd(&hist2[r], 1);
    stage[hbase[r] + p] = pk;
  }
  __syncthreads();
  for (int b = 0; b < NRANGES; b++){
    int len = hist[b];
    int gb = gbase[b], hb = hbase[b];
    for (int i = tid; i < len; i += 256) ebuf1[gb + i] = stage[hb + i];
  }
}

// ---------------- P2: per-range batch-sort into 50 buckets (full-line flushes) ----------------

__global__ __launch_bounds__(256) void k_p2(const u32* __restrict__ ebuf1, const int* __restrict__ range_cursor,
                                            int* __restrict__ bucket_cursor, u32* __restrict__ ebuf2){
  __shared__ u32 stage[BATCH];
  __shared__ int hist[50], hist2[50], hbase[50], gbase[50];
  const int tid = threadIdx.x;
  const int r = blockIdx.x / RBLK;
  const int chunk = blockIdx.x % RBLK;
  const int rlen = range_cursor[r] - r * RCAP;
  const int i0 = chunk * BATCH;
  const int len = min(BATCH, rlen - i0);
  if (len <= 0) return;
  const u32* seg = ebuf1 + (long)r * RCAP + i0;

  if (tid < 50){ hist[tid] = 0; hist2[tid] = 0; }
  __syncthreads();
  for (int i = tid; i < len; i += 256){
    int dl = (int)(seg[i] >> 18);
    atomicAdd(&hist[dl / BUCKET_N], 1);
  }
  __syncthreads();
  if (tid == 0){ int run = 0; for (int b = 0; b < 50; b++){ hbase[b] = run; run += hist[b]; } }
  __syncthreads();
  if (tid < 50 && hist[tid] > 0) gbase[tid] = atomicAdd(&bucket_cursor[r * 50 + tid], hist[tid]);
  __syncthreads();
  for (int i = tid; i < len; i += 256){
    u32 pk = seg[i];
    int b = (int)(pk >> 18) / BUCKET_N;
    int p = atomicAdd(&hist2[b], 1);
    stage[hbase[b] + p] = pk;
  }
  __syncthreads();
  for (int b = 0; b < 50; b++){
    int l = hist[b];
    if (l == 0) continue;
    int gb = gbase[b], hb = hbase[b];
    for (int i = tid; i < l; i += 256) ebuf2[gb + i] = stage[hb + i];
  }
}

// ---------------- scan of 800 bucket lengths -> bucket_base ----------------

__global__ __launch_bounds__(256) void k_scanb(const int* __restrict__ bucket_cursor,
                                               int* __restrict__ bucket_base){
  __shared__ int q[256];
  int tid = threadIdx.x;
  int v[4]; int sum4 = 0;
  if (tid < 200){
    #pragma unroll
    for (int j = 0; j < 4; j++){ int b = 4 * tid + j; v[j] = bucket_cursor[b] - b * BCAP; sum4 += v[j]; }
  }
  q[tid] = sum4; __syncthreads();
  for (int off = 1; off < 256; off <<= 1){
    int t = (tid >= off) ? q[tid - off] : 0;
    __syncthreads();
    q[tid] += t;
    __syncthreads();
  }
  if (tid < 200){
    int run = q[tid] - sum4;
    #pragma unroll
    for (int j = 0; j < 4; j++){ bucket_base[4 * tid + j] = run; run += v[j]; }
  }
}

// ---------------- P3: per-bucket LDS scatter; writes csr AND row_start ----------------

__global__ __launch_bounds__(256) void k_p3(const u32* __restrict__ ebuf2, const int* __restrict__ bucket_cursor,
                                            const int* __restrict__ bucket_base,
                                            int* __restrict__ csr, int* __restrict__ row_start){
  __shared__ int stage[BCAP];
  __shared__ int hist[BUCKET_N], sbase[BUCKET_N], cur[BUCKET_N];
  __shared__ int q[256];
  const int tid = threadIdx.x;
  const int b = blockIdx.x;
  const int n0 = b * BUCKET_N;
  const int dl0 = (b % 50) * BUCKET_N;
  const int len = min(bucket_cursor[b] - b * BCAP, BCAP);
  const int base = bucket_base[b];
  const u32* seg = ebuf2 + (long)b * BCAP;

  if (tid < BUCKET_N){ hist[tid] = 0; cur[tid] = 0; }
  __syncthreads();
  for (int i = tid; i < len; i += 256){
    int local = (int)(seg[i] >> 18) - dl0;
    local = min(max(local, 0), BUCKET_N - 1);   // safety clamp (statistically unreachable)
    atomicAdd(&hist[local], 1);
  }
  __syncthreads();
  {
    int v = (tid < BUCKET_N) ? hist[tid] : 0;
    q[tid] = v; __syncthreads();
    for (int off = 1; off < 256; off <<= 1){
      int t = (tid >= off) ? q[tid - off] : 0;
      __syncthreads();
      q[tid] += t;
      __syncthreads();
    }
    if (tid < BUCKET_N) sbase[tid] = q[tid] - v;
  }
  __syncthreads();
  for (int i = tid; i < len; i += 256){
    u32 pk = seg[i];
    int local = (int)(pk >> 18) - dl0;
    local = min(max(local, 0), BUCKET_N - 1);
    int pos = atomicAdd(&cur[local], 1);
    stage[sbase[local] + pos] = (int)(pk & 0x3FFFFu);
  }
  __syncthreads();
  for (int i = tid; i < len; i += 256) csr[base + i] = stage[i];
  if (tid < BUCKET_N) row_start[n0 + tid] = base + sbase[tid];
  if (b == NBUCKETS - 1 && tid == 0) row_start[N_NODES] = base + len;
}

// ---------------- GEMM [rows,128] @ [128,128] (first layer) -> bf16 xb only ----------------
// W staged in LDS in two 64-row fp32 halves: per-block W L2 traffic 512KB -> 64KB.

__global__ __launch_bounds__(256) void k_gemm128(const float* __restrict__ A,
    const float* __restrict__ W, const float* __restrict__ bias,
    u32* __restrict__ xbout)
{
  __shared__ float As[64][132];
  __shared__ float Wl[64][128];
  const int tid = threadIdx.x;
  const long row0 = (long)blockIdx.x * 64;

  const float4* A4 = (const float4*)(A + row0 * HID);
  for (int i = tid; i < 64 * 32; i += 256){
    int r = i >> 5, c = i & 31;
    *(float4*)&As[r][c * 4] = A4[r * 32 + c];
  }

  const int cg = tid & 31;
  const int rg = tid >> 5;
  const int c0 = cg * 4;
  float acc[8][4];
  {
    float4 b = *(const float4*)&bias[c0];
    #pragma unroll
    for (int r = 0; r < 8; r++){ acc[r][0]=b.x; acc[r][1]=b.y; acc[r][2]=b.z; acc[r][3]=b.w; }
  }

  for (int h = 0; h < 2; h++){
    __syncthreads();   // h=0: As written; h>0: previous Wl half fully consumed
    for (int i = tid; i < 64 * 32; i += 256){
      int kk = i >> 5, c = (i & 31) * 4;
      *(float4*)&Wl[kk][c] = *(const float4*)&W[(h * 64 + kk) * HID + c];
    }
    __syncthreads();
    for (int k = 0; k < 64; k += 4){
      float4 w0 = *(const float4*)&Wl[k + 0][c0];
      float4 w1 = *(const float4*)&Wl[k + 1][c0];
      float4 w2 = *(const float4*)&Wl[k + 2][c0];
      float4 w3 = *(const float4*)&Wl[k + 3][c0];
      #pragma unroll
      for (int r = 0; r < 8; r++){
        float4 a = *(const float4*)&As[rg * 8 + r][h * 64 + k];
        acc[r][0] = fmaf(a.w, w3.x, fmaf(a.z, w2.x, fmaf(a.y, w1.x, fmaf(a.x, w0.x, acc[r][0]))));
        acc[r][1] = fmaf(a.w, w3.y, fmaf(a.z, w2.y, fmaf(a.y, w1.y, fmaf(a.x, w0.y, acc[r][1]))));
        acc[r][2] = fmaf(a.w, w3.z, fmaf(a.z, w2.z, fmaf(a.y, w1.z, fmaf(a.x, w0.z, acc[r][2]))));
        acc[r][3] = fmaf(a.w, w3.w, fmaf(a.z, w2.w, fmaf(a.y, w1.w, fmaf(a.x, w0.w, acc[r][3]))));
      }
    }
  }

  #pragma unroll
  for (int r = 0; r < 8; r++){
    long row = row0 + rg * 8 + r;
    uint2 p; p.x = pack2bf(acc[r][0], acc[r][1]); p.y = pack2bf(acc[r][2], acc[r][3]);
    *(uint2*)&xbout[(row * HID + c0) >> 1] = p;
  }
}

// ---------------- fused layer: aggregate 32 nodes into LDS, then GEMM+relu+LN ----------------
// bf16-only inter-layer state; gather at the random-line fabric ceiling.
// Phase B: W staged in LDS (two 64-row fp32 halves) -> per-block W L2 traffic
// 512KB -> 64KB, freeing the TCC return path for the gather stream.
// LDS = As 16.9KB + Wl 32KB = 49.7KB -> 3 blocks/CU (24 waves).

__global__ __launch_bounds__(256) void k_fused(const int* __restrict__ row_start,
    const int* __restrict__ csr, const uint2* __restrict__ xb2,
    const float* __restrict__ W, const float* __restrict__ bias,
    const float* __restrict__ gamma, const float* __restrict__ beta,
    u32* __restrict__ xbout)
{
  __shared__ float As[FTILE][132];
  __shared__ float Wl[64][128];
  const int tid = threadIdx.x;
  const long row0 = (long)blockIdx.x * FTILE;

  // ---- Phase A: aggregation into As ----
  {
    const int wv = tid >> 6;
    const int lane = tid & 63;
    const int half = lane >> 5, col = lane & 31;
    const uint2* xbc = xb2 + col;

    for (int i = 0; i < FTILE / 4; i++){
      const int r = wv * (FTILE / 4) + i;
      const int node = (int)row0 + r;
      const int s0 = row_start[node], s1 = row_start[node + 1];

      float4 xs = {0.f, 0.f, 0.f, 0.f};
      if (half == 0){
        uint2 sv = xb2[(long)node * 32 + col];
        xs.x = __uint_as_float(sv.x << 16);
        xs.y = __uint_as_float(sv.x & 0xffff0000u);
        xs.z = __uint_as_float(sv.y << 16);
        xs.w = __uint_as_float(sv.y & 0xffff0000u);
      }

      float a0 = 0.f, a1 = 0.f, a2 = 0.f, a3 = 0.f;
      int base = s0;
      int idx[8];
      if (base + 16 <= s1){
        #pragma unroll
        for (int j = 0; j < 8; j++) idx[j] = csr[base + 2*j + half];
      }
      while (base + 16 <= s1){
        uint2 p[8];
        #pragma unroll
        for (int j = 0; j < 8; j++) p[j] = xbc[(long)idx[j] * 32];
        base += 16;
        if (base + 16 <= s1){
          #pragma unroll
          for (int j = 0; j < 8; j++) idx[j] = csr[base + 2*j + half];
        }
        #pragma unroll
        for (int j = 0; j < 8; j++){
          a0 += __uint_as_float(p[j].x << 16);
          a1 += __uint_as_float(p[j].x & 0xffff0000u);
          a2 += __uint_as_float(p[j].y << 16);
          a3 += __uint_as_float(p[j].y & 0xffff0000u);
        }
      }
      if (base < s1){
        const int s1m1 = s1 - 1;
        int ti[8];
        #pragma unroll
        for (int j = 0; j < 8; j++) ti[j] = csr[min(base + 2*j + half, s1m1)];
        uint2 p[8];
        #pragma unroll
        for (int j = 0; j < 8; j++) p[j] = xbc[(long)ti[j] * 32];
        #pragma unroll
        for (int j = 0; j < 8; j++){
          bool act = (base + 2*j + half) < s1;
          float v0 = __uint_as_float(p[j].x << 16);
          float v1 = __uint_as_float(p[j].x & 0xffff0000u);
          float v2 = __uint_as_float(p[j].y << 16);
          float v3 = __uint_as_float(p[j].y & 0xffff0000u);
          a0 += act ? v0 : 0.f;
          a1 += act ? v1 : 0.f;
          a2 += act ? v2 : 0.f;
          a3 += act ? v3 : 0.f;
        }
      }

      a0 += __shfl_down(a0, 32);
      a1 += __shfl_down(a1, 32);
      a2 += __shfl_down(a2, 32);
      a3 += __shfl_down(a3, 32);

      if (half == 0){
        float inv = 1.f / (float)(s1 - s0 + 1);
        float4 rv;
        rv.x = (a0 + xs.x) * inv;
        rv.y = (a1 + xs.y) * inv;
        rv.z = (a2 + xs.z) * inv;
        rv.w = (a3 + xs.w) * inv;
        *(float4*)&As[r][col * 4] = rv;
      }
    }
  }

  // ---- Phase B: GEMM + relu + LN (W from LDS; half-wave butterfly stats) ----
  const int cg = tid & 31;
  const int rg = tid >> 5;             // 0..7 -> 4 rows each
  const int c0 = cg * 4;
  float acc[4][4];
  {
    float4 b = *(const float4*)&bias[c0];
    #pragma unroll
    for (int r = 0; r < 4; r++){ acc[r][0]=b.x; acc[r][1]=b.y; acc[r][2]=b.z; acc[r][3]=b.w; }
  }

  for (int h = 0; h < 2; h++){
    __syncthreads();   // h=0: As written; h>0: previous Wl half fully consumed
    for (int i = tid; i < 64 * 32; i += 256){
      int kk = i >> 5, c = (i & 31) * 4;
      *(float4*)&Wl[kk][c] = *(const float4*)&W[(h * 64 + kk) * HID + c];
    }
    __syncthreads();
    for (int k = 0; k < 64; k += 4){
      float4 w0 = *(const float4*)&Wl[k + 0][c0];
      float4 w1 = *(const float4*)&Wl[k + 1][c0];
      float4 w2 = *(const float4*)&Wl[k + 2][c0];
      float4 w3 = *(const float4*)&Wl[k + 3][c0];
      #pragma unroll
      for (int r = 0; r < 4; r++){
        float4 a = *(const float4*)&As[rg * 4 + r][h * 64 + k];
        acc[r][0] = fmaf(a.w, w3.x, fmaf(a.z, w2.x, fmaf(a.y, w1.x, fmaf(a.x, w0.x, acc[r][0]))));
        acc[r][1] = fmaf(a.w, w3.y, fmaf(a.z, w2.y, fmaf(a.y, w1.y, fmaf(a.x, w0.y, acc[r][1]))));
        acc[r][2] = fmaf(a.w, w3.z, fmaf(a.z, w2.z, fmaf(a.y, w1.z, fmaf(a.x, w0.z, acc[r][2]))));
        acc[r][3] = fmaf(a.w, w3.w, fmaf(a.z, w2.w, fmaf(a.y, w1.w, fmaf(a.x, w0.w, acc[r][3]))));
      }
    }
  }

  // relu + per-row {sum, sumsq} partials over this thread's 4 cols
  float s[4], s2[4];
  #pragma unroll
  for (int r = 0; r < 4; r++){
    float v0 = fmaxf(acc[r][0], 0.f);
    float v1 = fmaxf(acc[r][1], 0.f);
    float v2 = fmaxf(acc[r][2], 0.f);
    float v3 = fmaxf(acc[r][3], 0.f);
    acc[r][0] = v0; acc[r][1] = v1; acc[r][2] = v2; acc[r][3] = v3;
    s[r]  = (v0 + v1) + (v2 + v3);
    s2[r] = fmaf(v0, v0, fmaf(v1, v1, fmaf(v2, v2, v3 * v3)));
  }
  // butterfly across the 32 lanes holding this row group (xor masks stay in half-wave)
  #pragma unroll
  for (int m = 1; m < 32; m <<= 1){
    #pragma unroll
    for (int r = 0; r < 4; r++){
      s[r]  += __shfl_xor(s[r],  m);
      s2[r] += __shfl_xor(s2[r], m);
    }
  }

  const float4 gm = *(const float4*)&gamma[c0];
  const float4 bt = *(const float4*)&beta[c0];
  #pragma unroll
  for (int r = 0; r < 4; r++){
    float mu = s[r] * (1.f / HID);
    float var = s2[r] * (1.f / HID) - mu * mu;
    float rs = 1.f / sqrtf(var + EPS);
    float4 v;
    v.x = (acc[r][0] - mu) * rs * gm.x + bt.x;
    v.y = (acc[r][1] - mu) * rs * gm.y + bt.y;
    v.z = (acc[r][2] - mu) * rs * gm.z + bt.z;
    v.w = (acc[r][3] - mu) * rs * gm.w + bt.w;
    long row = row0 + rg * 4 + r;
    uint2 p; p.x = pack2bf(v.x, v.y); p.y = pack2bf(v.z, v.w);
    *(uint2*)&xbout[(row * HID + c0) >> 1] = p;
  }
}

// ---------------- output GEMM [rows,128](bf16) @ [128,16] ----------------

__global__ __launch_bounds__(256) void k_gemm_out(const u32* __restrict__ xb,
    const float* __restrict__ Wo, const float* __restrict__ bo, float* __restrict__ out)
{
  __shared__ float As[16][132];
  __shared__ float Wl[HID * OUTF];
  const int tid = threadIdx.x;
  const long row0 = (long)blockIdx.x * 16;
  {
    // 16 rows x 16 uint4 (8 bf16 each) = 256 loads, one per thread
    int r = tid >> 4, u = tid & 15;
    uint4 v = ((const uint4*)xb)[(row0 + r) * 16 + u];
    float* d = &As[r][u * 8];
    d[0] = __uint_as_float(v.x << 16); d[1] = __uint_as_float(v.x & 0xffff0000u);
    d[2] = __uint_as_float(v.y << 16); d[3] = __uint_as_float(v.y & 0xffff0000u);
    d[4] = __uint_as_float(v.z << 16); d[5] = __uint_as_float(v.z & 0xffff0000u);
    d[6] = __uint_as_float(v.w << 16); d[7] = __uint_as_float(v.w & 0xffff0000u);
  }
  for (int i = tid; i < HID * OUTF; i += 256) Wl[i] = Wo[i];
  __syncthreads();
  int col = tid & 15, r = tid >> 4;
  float acc = bo[col];
  for (int k = 0; k < HID; k += 4){
    float4 a = *(const float4*)&As[r][k];
    acc = fmaf(a.x, Wl[(k + 0) * OUTF + col],
          fmaf(a.y, Wl[(k + 1) * OUTF + col],
          fmaf(a.z, Wl[(k + 2) * OUTF + col],
          fmaf(a.w, Wl[(k + 3) * OUTF + col], acc))));
  }
  out[(row0 + r) * OUTF + col] = acc;
}

// ---------------- launch ----------------

extern "C" void kernel_launch(void* const* d_in, const int* in_sizes, int n_in,
                              void* d_out, int out_size, void* d_ws, size_t ws_size,
                              hipStream_t stream)
{
  (void)in_sizes; (void)n_in; (void)out_size; (void)ws_size;
  const float* nodes = (const float*)d_in[0];
  const int*   src   = (const int*)d_in[1];
  const int*   dst   = (const int*)d_in[2];
  const float* W_in  = (const float*)d_in[3];
  const float* b_in  = (const float*)d_in[4];
  const float* Ws    = (const float*)d_in[5];
  const float* bs    = (const float*)d_in[6];
  const float* gam   = (const float*)d_in[7];
  const float* bet   = (const float*)d_in[8];
  const float* W_out = (const float*)d_in[9];
  const float* b_out = (const float*)d_in[10];
  float* out = (float*)d_out;

  size_t off = 0;
  auto bump = [&](size_t bytes) -> char* {
    char* p = (char*)d_ws + off;
    off = (off + bytes + 255) & ~(size_t)255;
    return p;
  };
  int* row_start     = (int*)bump((N_NODES + 1) * sizeof(int));
  int* range_cursor  = (int*)bump(NRANGES * sizeof(int));
  int* bucket_cursor = (int*)bump(NBUCKETS * sizeof(int));
  int* bucket_base   = (int*)bump((NBUCKETS + 1) * sizeof(int));
  int* csr           = (int*)bump((size_t)N_EDGES * sizeof(int));
  u32* xb0           = (u32*)bump((size_t)N_NODES * HID * sizeof(unsigned short));
  u32* xb1           = (u32*)bump((size_t)N_NODES * HID * sizeof(unsigned short));

  // ebuf1 (25.9MB) aliases xb0 (51.2MB): P2 consumes ebuf1 before gemm128 writes xb0.
  // ebuf2 (30.4MB) aliases xb1 (51.2MB): P3 consumes ebuf2 before layer-0 writes xb1.
  u32* ebuf1 = (u32*)xb0;
  u32* ebuf2 = (u32*)xb1;

  k_initcur<<<4, 256, 0, stream>>>(range_cursor, bucket_cursor);
  k_p1<<<NBATCH, 256, 0, stream>>>(src, dst, range_cursor, ebuf1);
  k_p2<<<NRANGES * RBLK, 256, 0, stream>>>(ebuf1, range_cursor, bucket_cursor, ebuf2);
  k_scanb<<<1, 256, 0, stream>>>(bucket_cursor, bucket_base);
  k_p3<<<NBUCKETS, 256, 0, stream>>>(ebuf2, bucket_cursor, bucket_base, csr, row_start);

  k_gemm128<<<N_NODES / 64, 256, 0, stream>>>(nodes, W_in, b_in, xb0);

  const u32* xbi = xb0; u32* xbo = xb1;
  for (int l = 0; l < LAYERS; l++){
    k_fused<<<N_NODES / FTILE, 256, 0, stream>>>(row_start, csr, (const uint2*)xbi,
                                                 Ws + (size_t)l * HID * HID, bs + l * HID,
                                                 gam + l * HID, bet + l * HID, xbo);
    const u32* tb = xbi; xbi = xbo; xbo = (u32*)tb;
  }

  k_gemm_out<<<N_NODES / 16, 256, 0, stream>>>(xbi, W_out, b_out, out);
}

// Round 7
// 1247.785 us; speedup vs baseline: 1.0739x; 1.0739x over previous
//
#include <hip/hip_runtime.h>

#define N_NODES 200000
#define N_EDGES 6400000
#define HID 128
#define OUTF 16
#define LAYERS 3
#define EPS 1e-5f

#define NRANGES 16
#define RANGE_N 12500                 // nodes per range
#define NBUCKETS 800
#define BUCKET_N 250                  // nodes per bucket
#define BATCH 5000                    // edges per sort batch
#define NBATCH (N_EDGES / BATCH)      // 1280
#define RCAP 405000                   // range segment capacity (mean 400000, sigma ~612)
#define RBLK (RCAP / BATCH)           // 81 P2 blocks per range
#define BCAP 9500                     // bucket segment capacity (mean 8000, sigma ~89)

#define FTILE 32                      // fused-layer tile rows (LDS 16.9KB -> 8 blocks/CU)

typedef unsigned int u32;

__device__ __forceinline__ unsigned short f2bf(float f){
  unsigned int u = __float_as_uint(f);
  u += 0x7fffu + ((u >> 16) & 1u);   // RNE
  return (unsigned short)(u >> 16);
}
__device__ __forceinline__ u32 pack2bf(float lo, float hi){
  return (u32)f2bf(lo) | ((u32)f2bf(hi) << 16);
}

// ---------------- cursor init ----------------

__global__ __launch_bounds__(256) void k_initcur(int* __restrict__ range_cursor,
                                                 int* __restrict__ bucket_cursor){
  int t = blockIdx.x * 256 + threadIdx.x;
  if (t < NRANGES) range_cursor[t] = t * RCAP;
  if (t < NBUCKETS) bucket_cursor[t] = t * BCAP;
}

// ---------------- FRONT: p1 (blocks 0..NBATCH-1) || gemm128 (rest) ----------------
// p1 and the input GEMM are data-independent; merging them overlaps p1's
// memory/LDS-atomic work with the GEMM's VALU work on the same CUs.
// LDS is a union: p1 needs 20.3KB, gemm needs As[64][132]=33.8KB -> 33.8KB.

__global__ __launch_bounds__(256) void k_front(const int* __restrict__ src, const int* __restrict__ dst,
    int* __restrict__ range_cursor, u32* __restrict__ ebuf1,
    const float* __restrict__ A, const float* __restrict__ W,
    const float* __restrict__ bias, u32* __restrict__ xbout)
{
  __shared__ __align__(16) char smraw[64 * 132 * 4];
  const int tid = threadIdx.x;

  if (blockIdx.x < NBATCH){
    // ---- P1: batch-sort edges into 16 dst ranges ----
    u32* stage = (u32*)smraw;                 // BATCH * 4 = 20000 B
    int* hist  = (int*)(smraw + 20000);       // 16
    int* hist2 = hist + 16;
    int* hbase = hist + 32;
    int* gbase = hist + 48;
    const long e0 = (long)blockIdx.x * BATCH;

    if (tid < NRANGES){ hist[tid] = 0; hist2[tid] = 0; }
    __syncthreads();
    for (int i = tid; i < BATCH; i += 256){
      int d = dst[e0 + i];
      atomicAdd(&hist[d / RANGE_N], 1);
    }
    __syncthreads();
    if (tid == 0){ int run = 0; for (int b = 0; b < NRANGES; b++){ hbase[b] = run; run += hist[b]; } }
    __syncthreads();
    if (tid < NRANGES && hist[tid] > 0) gbase[tid] = atomicAdd(&range_cursor[tid], hist[tid]);
    __syncthreads();
    for (int i = tid; i < BATCH; i += 256){
      int d = dst[e0 + i];
      int s = src[e0 + i];
      int r = d / RANGE_N;
      u32 pk = ((u32)(d - r * RANGE_N) << 18) | (u32)s;
      int p = atomicAdd(&hist2[r], 1);
      stage[hbase[r] + p] = pk;
    }
    __syncthreads();
    for (int b = 0; b < NRANGES; b++){
      int len = hist[b];
      int gb = gbase[b], hb = hbase[b];
      for (int i = tid; i < len; i += 256) ebuf1[gb + i] = stage[hb + i];
    }
    return;
  }

  // ---- input GEMM [64,128] @ [128,128] -> bf16 xb (round-5 body) ----
  float (*As)[132] = (float (*)[132])smraw;
  const long row0 = (long)(blockIdx.x - NBATCH) * 64;

  const float4* A4 = (const float4*)(A + row0 * HID);
  for (int i = tid; i < 64 * 32; i += 256){
    int r = i >> 5, c = i & 31;
    *(float4*)&As[r][c * 4] = A4[r * 32 + c];
  }
  __syncthreads();

  const int cg = tid & 31;
  const int rg = tid >> 5;
  const int c0 = cg * 4;
  float acc[8][4];
  {
    float4 b = *(const float4*)&bias[c0];
    #pragma unroll
    for (int r = 0; r < 8; r++){ acc[r][0]=b.x; acc[r][1]=b.y; acc[r][2]=b.z; acc[r][3]=b.w; }
  }

  for (int k = 0; k < HID; k += 4){
    float4 w0 = *(const float4*)&W[(k + 0) * HID + c0];
    float4 w1 = *(const float4*)&W[(k + 1) * HID + c0];
    float4 w2 = *(const float4*)&W[(k + 2) * HID + c0];
    float4 w3 = *(const float4*)&W[(k + 3) * HID + c0];
    #pragma unroll
    for (int r = 0; r < 8; r++){
      float4 a = *(const float4*)&As[rg * 8 + r][k];
      acc[r][0] = fmaf(a.w, w3.x, fmaf(a.z, w2.x, fmaf(a.y, w1.x, fmaf(a.x, w0.x, acc[r][0]))));
      acc[r][1] = fmaf(a.w, w3.y, fmaf(a.z, w2.y, fmaf(a.y, w1.y, fmaf(a.x, w0.y, acc[r][1]))));
      acc[r][2] = fmaf(a.w, w3.z, fmaf(a.z, w2.z, fmaf(a.y, w1.z, fmaf(a.x, w0.z, acc[r][2]))));
      acc[r][3] = fmaf(a.w, w3.w, fmaf(a.z, w2.w, fmaf(a.y, w1.w, fmaf(a.x, w0.w, acc[r][3]))));
    }
  }

  #pragma unroll
  for (int r = 0; r < 8; r++){
    long row = row0 + rg * 8 + r;
    uint2 p; p.x = pack2bf(acc[r][0], acc[r][1]); p.y = pack2bf(acc[r][2], acc[r][3]);
    *(uint2*)&xbout[(row * HID + c0) >> 1] = p;
  }
}

// ---------------- P2: per-range batch-sort into 50 buckets (full-line flushes) ----------------

__global__ __launch_bounds__(256) void k_p2(const u32* __restrict__ ebuf1, const int* __restrict__ range_cursor,
                                            int* __restrict__ bucket_cursor, u32* __restrict__ ebuf2){
  __shared__ u32 stage[BATCH];
  __shared__ int hist[50], hist2[50], hbase[50], gbase[50];
  const int tid = threadIdx.x;
  const int r = blockIdx.x / RBLK;
  const int chunk = blockIdx.x % RBLK;
  const int rlen = range_cursor[r] - r * RCAP;
  const int i0 = chunk * BATCH;
  const int len = min(BATCH, rlen - i0);
  if (len <= 0) return;
  const u32* seg = ebuf1 + (long)r * RCAP + i0;

  if (tid < 50){ hist[tid] = 0; hist2[tid] = 0; }
  __syncthreads();
  for (int i = tid; i < len; i += 256){
    int dl = (int)(seg[i] >> 18);
    atomicAdd(&hist[dl / BUCKET_N], 1);
  }
  __syncthreads();
  if (tid == 0){ int run = 0; for (int b = 0; b < 50; b++){ hbase[b] = run; run += hist[b]; } }
  __syncthreads();
  if (tid < 50 && hist[tid] > 0) gbase[tid] = atomicAdd(&bucket_cursor[r * 50 + tid], hist[tid]);
  __syncthreads();
  for (int i = tid; i < len; i += 256){
    u32 pk = seg[i];
    int b = (int)(pk >> 18) / BUCKET_N;
    int p = atomicAdd(&hist2[b], 1);
    stage[hbase[b] + p] = pk;
  }
  __syncthreads();
  for (int b = 0; b < 50; b++){
    int l = hist[b];
    if (l == 0) continue;
    int gb = gbase[b], hb = hbase[b];
    for (int i = tid; i < l; i += 256) ebuf2[gb + i] = stage[hb + i];
  }
}

// ---------------- scan of 800 bucket lengths -> bucket_base ----------------

__global__ __launch_bounds__(256) void k_scanb(const int* __restrict__ bucket_cursor,
                                               int* __restrict__ bucket_base){
  __shared__ int q[256];
  int tid = threadIdx.x;
  int v[4]; int sum4 = 0;
  if (tid < 200){
    #pragma unroll
    for (int j = 0; j < 4; j++){ int b = 4 * tid + j; v[j] = bucket_cursor[b] - b * BCAP; sum4 += v[j]; }
  }
  q[tid] = sum4; __syncthreads();
  for (int off = 1; off < 256; off <<= 1){
    int t = (tid >= off) ? q[tid - off] : 0;
    __syncthreads();
    q[tid] += t;
    __syncthreads();
  }
  if (tid < 200){
    int run = q[tid] - sum4;
    #pragma unroll
    for (int j = 0; j < 4; j++){ bucket_base[4 * tid + j] = run; run += v[j]; }
  }
}

// ---------------- P3: per-bucket LDS scatter; writes csr AND row_start ----------------

__global__ __launch_bounds__(256) void k_p3(const u32* __restrict__ ebuf2, const int* __restrict__ bucket_cursor,
                                            const int* __restrict__ bucket_base,
                                            int* __restrict__ csr, int* __restrict__ row_start){
  __shared__ int stage[BCAP];
  __shared__ int hist[BUCKET_N], sbase[BUCKET_N], cur[BUCKET_N];
  __shared__ int q[256];
  const int tid = threadIdx.x;
  const int b = blockIdx.x;
  const int n0 = b * BUCKET_N;
  const int dl0 = (b % 50) * BUCKET_N;
  const int len = min(bucket_cursor[b] - b * BCAP, BCAP);
  const int base = bucket_base[b];
  const u32* seg = ebuf2 + (long)b * BCAP;

  if (tid < BUCKET_N){ hist[tid] = 0; cur[tid] = 0; }
  __syncthreads();
  for (int i = tid; i < len; i += 256){
    int local = (int)(seg[i] >> 18) - dl0;
    local = min(max(local, 0), BUCKET_N - 1);   // safety clamp (statistically unreachable)
    atomicAdd(&hist[local], 1);
  }
  __syncthreads();
  {
    int v = (tid < BUCKET_N) ? hist[tid] : 0;
    q[tid] = v; __syncthreads();
    for (int off = 1; off < 256; off <<= 1){
      int t = (tid >= off) ? q[tid - off] : 0;
      __syncthreads();
      q[tid] += t;
      __syncthreads();
    }
    if (tid < BUCKET_N) sbase[tid] = q[tid] - v;
  }
  __syncthreads();
  for (int i = tid; i < len; i += 256){
    u32 pk = seg[i];
    int local = (int)(pk >> 18) - dl0;
    local = min(max(local, 0), BUCKET_N - 1);
    int pos = atomicAdd(&cur[local], 1);
    stage[sbase[local] + pos] = (int)(pk & 0x3FFFFu);
  }
  __syncthreads();
  for (int i = tid; i < len; i += 256) csr[base + i] = stage[i];
  if (tid < BUCKET_N) row_start[n0 + tid] = base + sbase[tid];
  if (b == NBUCKETS - 1 && tid == 0) row_start[N_NODES] = base + len;
}

// ---------------- gather phase (shared by k_fused / k_fused_out) ----------------
// 4 waves x 8 nodes; per-node uint2 gather (16 edges/iter, csr prefetch,
// unmasked bulk + masked tail); aggregated fp32 row -> As. (round-5 proven body)

__device__ __forceinline__ void agg_tile(const int* __restrict__ row_start,
    const int* __restrict__ csr, const uint2* __restrict__ xb2,
    long row0, int tid, float (*As)[132])
{
  const int wv = tid >> 6;
  const int lane = tid & 63;
  const int half = lane >> 5, col = lane & 31;
  const uint2* xbc = xb2 + col;

  for (int i = 0; i < FTILE / 4; i++){
    const int r = wv * (FTILE / 4) + i;
    const int node = (int)row0 + r;
    const int s0 = row_start[node], s1 = row_start[node + 1];

    float4 xs = {0.f, 0.f, 0.f, 0.f};
    if (half == 0){
      uint2 sv = xb2[(long)node * 32 + col];
      xs.x = __uint_as_float(sv.x << 16);
      xs.y = __uint_as_float(sv.x & 0xffff0000u);
      xs.z = __uint_as_float(sv.y << 16);
      xs.w = __uint_as_float(sv.y & 0xffff0000u);
    }

    float a0 = 0.f, a1 = 0.f, a2 = 0.f, a3 = 0.f;
    int base = s0;
    int idx[8];
    if (base + 16 <= s1){
      #pragma unroll
      for (int j = 0; j < 8; j++) idx[j] = csr[base + 2*j + half];
    }
    while (base + 16 <= s1){
      uint2 p[8];
      #pragma unroll
      for (int j = 0; j < 8; j++) p[j] = xbc[(long)idx[j] * 32];
      base += 16;
      if (base + 16 <= s1){
        #pragma unroll
        for (int j = 0; j < 8; j++) idx[j] = csr[base + 2*j + half];
      }
      #pragma unroll
      for (int j = 0; j < 8; j++){
        a0 += __uint_as_float(p[j].x << 16);
        a1 += __uint_as_float(p[j].x & 0xffff0000u);
        a2 += __uint_as_float(p[j].y << 16);
        a3 += __uint_as_float(p[j].y & 0xffff0000u);
      }
    }
    if (base < s1){
      const int s1m1 = s1 - 1;
      int ti[8];
      #pragma unroll
      for (int j = 0; j < 8; j++) ti[j] = csr[min(base + 2*j + half, s1m1)];
      uint2 p[8];
      #pragma unroll
      for (int j = 0; j < 8; j++) p[j] = xbc[(long)ti[j] * 32];
      #pragma unroll
      for (int j = 0; j < 8; j++){
        bool act = (base + 2*j + half) < s1;
        float v0 = __uint_as_float(p[j].x << 16);
        float v1 = __uint_as_float(p[j].x & 0xffff0000u);
        float v2 = __uint_as_float(p[j].y << 16);
        float v3 = __uint_as_float(p[j].y & 0xffff0000u);
        a0 += act ? v0 : 0.f;
        a1 += act ? v1 : 0.f;
        a2 += act ? v2 : 0.f;
        a3 += act ? v3 : 0.f;
      }
    }

    a0 += __shfl_down(a0, 32);
    a1 += __shfl_down(a1, 32);
    a2 += __shfl_down(a2, 32);
    a3 += __shfl_down(a3, 32);

    if (half == 0){
      float inv = 1.f / (float)(s1 - s0 + 1);
      float4 rv;
      rv.x = (a0 + xs.x) * inv;
      rv.y = (a1 + xs.y) * inv;
      rv.z = (a2 + xs.z) * inv;
      rv.w = (a3 + xs.w) * inv;
      *(float4*)&As[r][col * 4] = rv;
    }
  }
}

// ---------------- fused layer (layers 0..L-2): agg -> GEMM+relu+LN -> bf16 xb ----------------

__global__ __launch_bounds__(256) void k_fused(const int* __restrict__ row_start,
    const int* __restrict__ csr, const uint2* __restrict__ xb2,
    const float* __restrict__ W, const float* __restrict__ bias,
    const float* __restrict__ gamma, const float* __restrict__ beta,
    u32* __restrict__ xbout)
{
  __shared__ float As[FTILE][132];
  const int tid = threadIdx.x;
  const long row0 = (long)blockIdx.x * FTILE;

  agg_tile(row_start, csr, xb2, row0, tid, As);
  __syncthreads();

  const int cg = tid & 31;
  const int rg = tid >> 5;             // 0..7 -> 4 rows each
  const int c0 = cg * 4;
  float acc[4][4];
  {
    float4 b = *(const float4*)&bias[c0];
    #pragma unroll
    for (int r = 0; r < 4; r++){ acc[r][0]=b.x; acc[r][1]=b.y; acc[r][2]=b.z; acc[r][3]=b.w; }
  }

  for (int k = 0; k < HID; k += 4){
    float4 w0 = *(const float4*)&W[(k + 0) * HID + c0];
    float4 w1 = *(const float4*)&W[(k + 1) * HID + c0];
    float4 w2 = *(const float4*)&W[(k + 2) * HID + c0];
    float4 w3 = *(const float4*)&W[(k + 3) * HID + c0];
    #pragma unroll
    for (int r = 0; r < 4; r++){
      float4 a = *(const float4*)&As[rg * 4 + r][k];
      acc[r][0] = fmaf(a.w, w3.x, fmaf(a.z, w2.x, fmaf(a.y, w1.x, fmaf(a.x, w0.x, acc[r][0]))));
      acc[r][1] = fmaf(a.w, w3.y, fmaf(a.z, w2.y, fmaf(a.y, w1.y, fmaf(a.x, w0.y, acc[r][1]))));
      acc[r][2] = fmaf(a.w, w3.z, fmaf(a.z, w2.z, fmaf(a.y, w1.z, fmaf(a.x, w0.z, acc[r][2]))));
      acc[r][3] = fmaf(a.w, w3.w, fmaf(a.z, w2.w, fmaf(a.y, w1.w, fmaf(a.x, w0.w, acc[r][3]))));
    }
  }

  float s[4], s2[4];
  #pragma unroll
  for (int r = 0; r < 4; r++){
    float v0 = fmaxf(acc[r][0], 0.f);
    float v1 = fmaxf(acc[r][1], 0.f);
    float v2 = fmaxf(acc[r][2], 0.f);
    float v3 = fmaxf(acc[r][3], 0.f);
    acc[r][0] = v0; acc[r][1] = v1; acc[r][2] = v2; acc[r][3] = v3;
    s[r]  = (v0 + v1) + (v2 + v3);
    s2[r] = fmaf(v0, v0, fmaf(v1, v1, fmaf(v2, v2, v3 * v3)));
  }
  #pragma unroll
  for (int m = 1; m < 32; m <<= 1){
    #pragma unroll
    for (int r = 0; r < 4; r++){
      s[r]  += __shfl_xor(s[r],  m);
      s2[r] += __shfl_xor(s2[r], m);
    }
  }

  const float4 gm = *(const float4*)&gamma[c0];
  const float4 bt = *(const float4*)&beta[c0];
  #pragma unroll
  for (int r = 0; r < 4; r++){
    float mu = s[r] * (1.f / HID);
    float var = s2[r] * (1.f / HID) - mu * mu;
    float rs = 1.f / sqrtf(var + EPS);
    float4 v;
    v.x = (acc[r][0] - mu) * rs * gm.x + bt.x;
    v.y = (acc[r][1] - mu) * rs * gm.y + bt.y;
    v.z = (acc[r][2] - mu) * rs * gm.z + bt.z;
    v.w = (acc[r][3] - mu) * rs * gm.w + bt.w;
    long row = row0 + rg * 4 + r;
    uint2 p; p.x = pack2bf(v.x, v.y); p.y = pack2bf(v.z, v.w);
    *(uint2*)&xbout[(row * HID + c0) >> 1] = p;
  }
}

// ---------------- last fused layer: agg -> GEMM+relu+LN -> output GEMM [128,16] ----------------
// No xb write (dead); normalized rows rounded to bf16 (matching what k_gemm_out
// would have read) staged in As; per-thread 2 output dots with Wo from global
// (8KB, L2/L1-hot). LDS unchanged (16.9KB) -> same occupancy as k_fused.

__global__ __launch_bounds__(256) void k_fused_out(const int* __restrict__ row_start,
    const int* __restrict__ csr, const uint2* __restrict__ xb2,
    const float* __restrict__ W, const float* __restrict__ bias,
    const float* __restrict__ gamma, const float* __restrict__ beta,
    const float* __restrict__ Wo, const float* __restrict__ bo,
    float* __restrict__ out)
{
  __shared__ float As[FTILE][132];
  const int tid = threadIdx.x;
  const long row0 = (long)blockIdx.x * FTILE;

  agg_tile(row_start, csr, xb2, row0, tid, As);
  __syncthreads();

  const int cg = tid & 31;
  const int rg = tid >> 5;
  const int c0 = cg * 4;
  float acc[4][4];
  {
    float4 b = *(const float4*)&bias[c0];
    #pragma unroll
    for (int r = 0; r < 4; r++){ acc[r][0]=b.x; acc[r][1]=b.y; acc[r][2]=b.z; acc[r][3]=b.w; }
  }

  for (int k = 0; k < HID; k += 4){
    float4 w0 = *(const float4*)&W[(k + 0) * HID + c0];
    float4 w1 = *(const float4*)&W[(k + 1) * HID + c0];
    float4 w2 = *(const float4*)&W[(k + 2) * HID + c0];
    float4 w3 = *(const float4*)&W[(k + 3) * HID + c0];
    #pragma unroll
    for (int r = 0; r < 4; r++){
      float4 a = *(const float4*)&As[rg * 4 + r][k];
      acc[r][0] = fmaf(a.w, w3.x, fmaf(a.z, w2.x, fmaf(a.y, w1.x, fmaf(a.x, w0.x, acc[r][0]))));
      acc[r][1] = fmaf(a.w, w3.y, fmaf(a.z, w2.y, fmaf(a.y, w1.y, fmaf(a.x, w0.y, acc[r][1]))));
      acc[r][2] = fmaf(a.w, w3.z, fmaf(a.z, w2.z, fmaf(a.y, w1.z, fmaf(a.x, w0.z, acc[r][2]))));
      acc[r][3] = fmaf(a.w, w3.w, fmaf(a.z, w2.w, fmaf(a.y, w1.w, fmaf(a.x, w0.w, acc[r][3]))));
    }
  }

  float s[4], s2[4];
  #pragma unroll
  for (int r = 0; r < 4; r++){
    float v0 = fmaxf(acc[r][0], 0.f);
    float v1 = fmaxf(acc[r][1], 0.f);
    float v2 = fmaxf(acc[r][2], 0.f);
    float v3 = fmaxf(acc[r][3], 0.f);
    acc[r][0] = v0; acc[r][1] = v1; acc[r][2] = v2; acc[r][3] = v3;
    s[r]  = (v0 + v1) + (v2 + v3);
    s2[r] = fmaf(v0, v0, fmaf(v1, v1, fmaf(v2, v2, v3 * v3)));
  }
  #pragma unroll
  for (int m = 1; m < 32; m <<= 1){
    #pragma unroll
    for (int r = 0; r < 4; r++){
      s[r]  += __shfl_xor(s[r],  m);
      s2[r] += __shfl_xor(s2[r], m);
    }
  }

  const float4 gm = *(const float4*)&gamma[c0];
  const float4 bt = *(const float4*)&beta[c0];
  __syncthreads();   // all As reads of the GEMM phase done before overwrite
  #pragma unroll
  for (int r = 0; r < 4; r++){
    float mu = s[r] * (1.f / HID);
    float var = s2[r] * (1.f / HID) - mu * mu;
    float rs = 1.f / sqrtf(var + EPS);
    float4 v;
    v.x = (acc[r][0] - mu) * rs * gm.x + bt.x;
    v.y = (acc[r][1] - mu) * rs * gm.y + bt.y;
    v.z = (acc[r][2] - mu) * rs * gm.z + bt.z;
    v.w = (acc[r][3] - mu) * rs * gm.w + bt.w;
    // round to bf16 exactly as k_gemm_out would have read from xb
    u32 plo = pack2bf(v.x, v.y), phi = pack2bf(v.z, v.w);
    float4 vb;
    vb.x = __uint_as_float(plo << 16); vb.y = __uint_as_float(plo & 0xffff0000u);
    vb.z = __uint_as_float(phi << 16); vb.w = __uint_as_float(phi & 0xffff0000u);
    *(float4*)&As[rg * 4 + r][c0] = vb;
  }
  __syncthreads();

  // output projection: 32 rows x 16 cols = 512 outs, 2 per thread
  {
    int col = tid & 15, rr = tid >> 4;   // rr 0..15
    #pragma unroll
    for (int rep = 0; rep < 2; rep++){
      int r = rr + rep * 16;
      float acco = bo[col];
      for (int k = 0; k < HID; k += 4){
        float4 a = *(const float4*)&As[r][k];
        acco = fmaf(a.x, Wo[(k + 0) * OUTF + col],
               fmaf(a.y, Wo[(k + 1) * OUTF + col],
               fmaf(a.z, Wo[(k + 2) * OUTF + col],
               fmaf(a.w, Wo[(k + 3) * OUTF + col], acco))));
      }
      out[(row0 + r) * OUTF + col] = acco;
    }
  }
}

// ---------------- launch ----------------

extern "C" void kernel_launch(void* const* d_in, const int* in_sizes, int n_in,
                              void* d_out, int out_size, void* d_ws, size_t ws_size,
                              hipStream_t stream)
{
  (void)in_sizes; (void)n_in; (void)out_size; (void)ws_size;
  const float* nodes = (const float*)d_in[0];
  const int*   src   = (const int*)d_in[1];
  const int*   dst   = (const int*)d_in[2];
  const float* W_in  = (const float*)d_in[3];
  const float* b_in  = (const float*)d_in[4];
  const float* Ws    = (const float*)d_in[5];
  const float* bs    = (const float*)d_in[6];
  const float* gam   = (const float*)d_in[7];
  const float* bet   = (const float*)d_in[8];
  const float* W_out = (const float*)d_in[9];
  const float* b_out = (const float*)d_in[10];
  float* out = (float*)d_out;

  size_t off = 0;
  auto bump = [&](size_t bytes) -> char* {
    char* p = (char*)d_ws + off;
    off = (off + bytes + 255) & ~(size_t)255;
    return p;
  };
  int* row_start     = (int*)bump((N_NODES + 1) * sizeof(int));
  int* range_cursor  = (int*)bump(NRANGES * sizeof(int));
  int* bucket_cursor = (int*)bump(NBUCKETS * sizeof(int));
  int* bucket_base   = (int*)bump((NBUCKETS + 1) * sizeof(int));
  int* csr           = (int*)bump((size_t)N_EDGES * sizeof(int));
  u32* xb0           = (u32*)bump((size_t)N_NODES * HID * sizeof(unsigned short));
  u32* xb1           = (u32*)bump((size_t)N_NODES * HID * sizeof(unsigned short));
  u32* ebuf1         = (u32*)bump((size_t)NRANGES * RCAP * sizeof(u32));  // own buffer: front writes xb0 concurrently

  // ebuf2 (30.4MB) aliases xb1 (51.2MB): P3 consumes ebuf2 before layer-0 writes xb1.
  u32* ebuf2 = (u32*)xb1;

  k_initcur<<<4, 256, 0, stream>>>(range_cursor, bucket_cursor);
  k_front<<<NBATCH + N_NODES / 64, 256, 0, stream>>>(src, dst, range_cursor, ebuf1,
                                                     nodes, W_in, b_in, xb0);
  k_p2<<<NRANGES * RBLK, 256, 0, stream>>>(ebuf1, range_cursor, bucket_cursor, ebuf2);
  k_scanb<<<1, 256, 0, stream>>>(bucket_cursor, bucket_base);
  k_p3<<<NBUCKETS, 256, 0, stream>>>(ebuf2, bucket_cursor, bucket_base, csr, row_start);

  const u32* xbi = xb0; u32* xbo = xb1;
  for (int l = 0; l < LAYERS - 1; l++){
    k_fused<<<N_NODES / FTILE, 256, 0, stream>>>(row_start, csr, (const uint2*)xbi,
                                                 Ws + (size_t)l * HID * HID, bs + l * HID,
                                                 gam + l * HID, bet + l * HID, xbo);
    const u32* tb = xbi; xbi = xbo; xbo = (u32*)tb;
  }
  k_fused_out<<<N_NODES / FTILE, 256, 0, stream>>>(row_start, csr, (const uint2*)xbi,
                                                   Ws + (size_t)(LAYERS - 1) * HID * HID,
                                                   bs + (LAYERS - 1) * HID,
                                                   gam + (LAYERS - 1) * HID,
                                                   bet + (LAYERS - 1) * HID,
                                                   W_out, b_out, out);
}

// Round 8
// 1232.859 us; speedup vs baseline: 1.0869x; 1.0121x over previous
//
#include <hip/hip_runtime.h>

#define N_NODES 200000
#define N_EDGES 6400000
#define HID 128
#define OUTF 16
#define LAYERS 3
#define EPS 1e-5f

#define NRANGES 16
#define RANGE_N 12500                 // nodes per range
#define NBUCKETS 800
#define BUCKET_N 250                  // nodes per bucket
#define BATCH 5000                    // edges per sort batch
#define NBATCH (N_EDGES / BATCH)      // 1280
#define RCAP 405000                   // range segment capacity (mean 400000, sigma ~612)
#define RBLK (RCAP / BATCH)           // 81 P2 blocks per range
#define BCAP 9500                     // bucket segment capacity (mean 8000, sigma ~89)

#define FTILE 32                      // fused-layer tile rows (LDS 16.9KB -> 8 blocks/CU)

typedef unsigned int u32;

__device__ __forceinline__ unsigned short f2bf(float f){
  unsigned int u = __float_as_uint(f);
  u += 0x7fffu + ((u >> 16) & 1u);   // RNE
  return (unsigned short)(u >> 16);
}
__device__ __forceinline__ u32 pack2bf(float lo, float hi){
  return (u32)f2bf(lo) | ((u32)f2bf(hi) << 16);
}

// ---------------- cursor init ----------------

__global__ __launch_bounds__(256) void k_initcur(int* __restrict__ range_cursor,
                                                 int* __restrict__ bucket_cursor){
  int t = blockIdx.x * 256 + threadIdx.x;
  if (t < NRANGES) range_cursor[t] = t * RCAP;
  if (t < NBUCKETS) bucket_cursor[t] = t * BCAP;
}

// ---------------- FRONT: p1 (blocks 0..NBATCH-1) || gemm128 (rest) ----------------
// p1 and the input GEMM are data-independent; merging them overlaps p1's
// memory/LDS-atomic work with the GEMM's VALU work on the same CUs.

__global__ __launch_bounds__(256) void k_front(const int* __restrict__ src, const int* __restrict__ dst,
    int* __restrict__ range_cursor, u32* __restrict__ ebuf1,
    const float* __restrict__ A, const float* __restrict__ W,
    const float* __restrict__ bias, u32* __restrict__ xbout)
{
  __shared__ __align__(16) char smraw[64 * 132 * 4];
  const int tid = threadIdx.x;

  if (blockIdx.x < NBATCH){
    // ---- P1: batch-sort edges into 16 dst ranges ----
    u32* stage = (u32*)smraw;                 // BATCH * 4 = 20000 B
    int* hist  = (int*)(smraw + 20000);       // 16
    int* hist2 = hist + 16;
    int* hbase = hist + 32;
    int* gbase = hist + 48;
    const long e0 = (long)blockIdx.x * BATCH;

    if (tid < NRANGES){ hist[tid] = 0; hist2[tid] = 0; }
    __syncthreads();
    for (int i = tid; i < BATCH; i += 256){
      int d = dst[e0 + i];
      atomicAdd(&hist[d / RANGE_N], 1);
    }
    __syncthreads();
    if (tid == 0){ int run = 0; for (int b = 0; b < NRANGES; b++){ hbase[b] = run; run += hist[b]; } }
    __syncthreads();
    if (tid < NRANGES && hist[tid] > 0) gbase[tid] = atomicAdd(&range_cursor[tid], hist[tid]);
    __syncthreads();
    for (int i = tid; i < BATCH; i += 256){
      int d = dst[e0 + i];
      int s = src[e0 + i];
      int r = d / RANGE_N;
      u32 pk = ((u32)(d - r * RANGE_N) << 18) | (u32)s;
      int p = atomicAdd(&hist2[r], 1);
      stage[hbase[r] + p] = pk;
    }
    __syncthreads();
    for (int b = 0; b < NRANGES; b++){
      int len = hist[b];
      int gb = gbase[b], hb = hbase[b];
      for (int i = tid; i < len; i += 256) ebuf1[gb + i] = stage[hb + i];
    }
    return;
  }

  // ---- input GEMM [64,128] @ [128,128] -> bf16 xb ----
  float (*As)[132] = (float (*)[132])smraw;
  const long row0 = (long)(blockIdx.x - NBATCH) * 64;

  const float4* A4 = (const float4*)(A + row0 * HID);
  for (int i = tid; i < 64 * 32; i += 256){
    int r = i >> 5, c = i & 31;
    *(float4*)&As[r][c * 4] = A4[r * 32 + c];
  }
  __syncthreads();

  const int cg = tid & 31;
  const int rg = tid >> 5;
  const int c0 = cg * 4;
  float acc[8][4];
  {
    float4 b = *(const float4*)&bias[c0];
    #pragma unroll
    for (int r = 0; r < 8; r++){ acc[r][0]=b.x; acc[r][1]=b.y; acc[r][2]=b.z; acc[r][3]=b.w; }
  }

  for (int k = 0; k < HID; k += 4){
    float4 w0 = *(const float4*)&W[(k + 0) * HID + c0];
    float4 w1 = *(const float4*)&W[(k + 1) * HID + c0];
    float4 w2 = *(const float4*)&W[(k + 2) * HID + c0];
    float4 w3 = *(const float4*)&W[(k + 3) * HID + c0];
    #pragma unroll
    for (int r = 0; r < 8; r++){
      float4 a = *(const float4*)&As[rg * 8 + r][k];
      acc[r][0] = fmaf(a.w, w3.x, fmaf(a.z, w2.x, fmaf(a.y, w1.x, fmaf(a.x, w0.x, acc[r][0]))));
      acc[r][1] = fmaf(a.w, w3.y, fmaf(a.z, w2.y, fmaf(a.y, w1.y, fmaf(a.x, w0.y, acc[r][1]))));
      acc[r][2] = fmaf(a.w, w3.z, fmaf(a.z, w2.z, fmaf(a.y, w1.z, fmaf(a.x, w0.z, acc[r][2]))));
      acc[r][3] = fmaf(a.w, w3.w, fmaf(a.z, w2.w, fmaf(a.y, w1.w, fmaf(a.x, w0.w, acc[r][3]))));
    }
  }

  #pragma unroll
  for (int r = 0; r < 8; r++){
    long row = row0 + rg * 8 + r;
    uint2 p; p.x = pack2bf(acc[r][0], acc[r][1]); p.y = pack2bf(acc[r][2], acc[r][3]);
    *(uint2*)&xbout[(row * HID + c0) >> 1] = p;
  }
}

// ---------------- P2: per-range batch-sort into 50 buckets (full-line flushes) ----------------

__global__ __launch_bounds__(256) void k_p2(const u32* __restrict__ ebuf1, const int* __restrict__ range_cursor,
                                            int* __restrict__ bucket_cursor, u32* __restrict__ ebuf2){
  __shared__ u32 stage[BATCH];
  __shared__ int hist[50], hist2[50], hbase[50], gbase[50];
  const int tid = threadIdx.x;
  const int r = blockIdx.x / RBLK;
  const int chunk = blockIdx.x % RBLK;
  const int rlen = range_cursor[r] - r * RCAP;
  const int i0 = chunk * BATCH;
  const int len = min(BATCH, rlen - i0);
  if (len <= 0) return;
  const u32* seg = ebuf1 + (long)r * RCAP + i0;

  if (tid < 50){ hist[tid] = 0; hist2[tid] = 0; }
  __syncthreads();
  for (int i = tid; i < len; i += 256){
    int dl = (int)(seg[i] >> 18);
    atomicAdd(&hist[dl / BUCKET_N], 1);
  }
  __syncthreads();
  if (tid == 0){ int run = 0; for (int b = 0; b < 50; b++){ hbase[b] = run; run += hist[b]; } }
  __syncthreads();
  if (tid < 50 && hist[tid] > 0) gbase[tid] = atomicAdd(&bucket_cursor[r * 50 + tid], hist[tid]);
  __syncthreads();
  for (int i = tid; i < len; i += 256){
    u32 pk = seg[i];
    int b = (int)(pk >> 18) / BUCKET_N;
    int p = atomicAdd(&hist2[b], 1);
    stage[hbase[b] + p] = pk;
  }
  __syncthreads();
  for (int b = 0; b < 50; b++){
    int l = hist[b];
    if (l == 0) continue;
    int gb = gbase[b], hb = hbase[b];
    for (int i = tid; i < l; i += 256) ebuf2[gb + i] = stage[hb + i];
  }
}

// ---------------- P3: per-bucket LDS scatter; computes own base (scanb folded in) ----------------

__global__ __launch_bounds__(256) void k_p3(const u32* __restrict__ ebuf2, const int* __restrict__ bucket_cursor,
                                            int* __restrict__ csr, int* __restrict__ row_start){
  __shared__ int stage[BCAP];
  __shared__ int hist[BUCKET_N], sbase[BUCKET_N], cur[BUCKET_N];
  __shared__ int q[256];
  __shared__ int base_s;
  const int tid = threadIdx.x;
  const int b = blockIdx.x;
  const int n0 = b * BUCKET_N;
  const int dl0 = (b % 50) * BUCKET_N;
  const int len = min(bucket_cursor[b] - b * BCAP, BCAP);
  const u32* seg = ebuf2 + (long)b * BCAP;

  // ---- bucket_base via in-block reduction over buckets < b (800 L2-hot ints) ----
  {
    int partial = 0;
    for (int i = tid; i < b; i += 256) partial += bucket_cursor[i] - i * BCAP;
    q[tid] = partial; __syncthreads();
    for (int off = 128; off > 0; off >>= 1){
      if (tid < off) q[tid] += q[tid + off];
      __syncthreads();
    }
    if (tid == 0) base_s = q[0];
  }

  if (tid < BUCKET_N){ hist[tid] = 0; cur[tid] = 0; }
  __syncthreads();
  const int base = base_s;
  for (int i = tid; i < len; i += 256){
    int local = (int)(seg[i] >> 18) - dl0;
    local = min(max(local, 0), BUCKET_N - 1);   // safety clamp (statistically unreachable)
    atomicAdd(&hist[local], 1);
  }
  __syncthreads();
  {
    int v = (tid < BUCKET_N) ? hist[tid] : 0;
    q[tid] = v; __syncthreads();
    for (int off = 1; off < 256; off <<= 1){
      int t = (tid >= off) ? q[tid - off] : 0;
      __syncthreads();
      q[tid] += t;
      __syncthreads();
    }
    if (tid < BUCKET_N) sbase[tid] = q[tid] - v;
  }
  __syncthreads();
  for (int i = tid; i < len; i += 256){
    u32 pk = seg[i];
    int local = (int)(pk >> 18) - dl0;
    local = min(max(local, 0), BUCKET_N - 1);
    int pos = atomicAdd(&cur[local], 1);
    stage[sbase[local] + pos] = (int)(pk & 0x3FFFFu);
  }
  __syncthreads();
  for (int i = tid; i < len; i += 256) csr[base + i] = stage[i];
  if (tid < BUCKET_N) row_start[n0 + tid] = base + sbase[tid];
  if (b == NBUCKETS - 1 && tid == 0) row_start[N_NODES] = base + len;
}

// ---------------- gather phase (round-5 proven body) ----------------

__device__ __forceinline__ void agg_tile(const int* __restrict__ row_start,
    const int* __restrict__ csr, const uint2* __restrict__ xb2,
    long row0, int tid, float (*As)[132])
{
  const int wv = tid >> 6;
  const int lane = tid & 63;
  const int half = lane >> 5, col = lane & 31;
  const uint2* xbc = xb2 + col;

  for (int i = 0; i < FTILE / 4; i++){
    const int r = wv * (FTILE / 4) + i;
    const int node = (int)row0 + r;
    const int s0 = row_start[node], s1 = row_start[node + 1];

    float4 xs = {0.f, 0.f, 0.f, 0.f};
    if (half == 0){
      uint2 sv = xb2[(long)node * 32 + col];
      xs.x = __uint_as_float(sv.x << 16);
      xs.y = __uint_as_float(sv.x & 0xffff0000u);
      xs.z = __uint_as_float(sv.y << 16);
      xs.w = __uint_as_float(sv.y & 0xffff0000u);
    }

    float a0 = 0.f, a1 = 0.f, a2 = 0.f, a3 = 0.f;
    int base = s0;
    int idx[8];
    if (base + 16 <= s1){
      #pragma unroll
      for (int j = 0; j < 8; j++) idx[j] = csr[base + 2*j + half];
    }
    while (base + 16 <= s1){
      uint2 p[8];
      #pragma unroll
      for (int j = 0; j < 8; j++) p[j] = xbc[(long)idx[j] * 32];
      base += 16;
      if (base + 16 <= s1){
        #pragma unroll
        for (int j = 0; j < 8; j++) idx[j] = csr[base + 2*j + half];
      }
      #pragma unroll
      for (int j = 0; j < 8; j++){
        a0 += __uint_as_float(p[j].x << 16);
        a1 += __uint_as_float(p[j].x & 0xffff0000u);
        a2 += __uint_as_float(p[j].y << 16);
        a3 += __uint_as_float(p[j].y & 0xffff0000u);
      }
    }
    if (base < s1){
      const int s1m1 = s1 - 1;
      int ti[8];
      #pragma unroll
      for (int j = 0; j < 8; j++) ti[j] = csr[min(base + 2*j + half, s1m1)];
      uint2 p[8];
      #pragma unroll
      for (int j = 0; j < 8; j++) p[j] = xbc[(long)ti[j] * 32];
      #pragma unroll
      for (int j = 0; j < 8; j++){
        bool act = (base + 2*j + half) < s1;
        float v0 = __uint_as_float(p[j].x << 16);
        float v1 = __uint_as_float(p[j].x & 0xffff0000u);
        float v2 = __uint_as_float(p[j].y << 16);
        float v3 = __uint_as_float(p[j].y & 0xffff0000u);
        a0 += act ? v0 : 0.f;
        a1 += act ? v1 : 0.f;
        a2 += act ? v2 : 0.f;
        a3 += act ? v3 : 0.f;
      }
    }

    a0 += __shfl_down(a0, 32);
    a1 += __shfl_down(a1, 32);
    a2 += __shfl_down(a2, 32);
    a3 += __shfl_down(a3, 32);

    if (half == 0){
      float inv = 1.f / (float)(s1 - s0 + 1);
      float4 rv;
      rv.x = (a0 + xs.x) * inv;
      rv.y = (a1 + xs.y) * inv;
      rv.z = (a2 + xs.z) * inv;
      rv.w = (a3 + xs.w) * inv;
      *(float4*)&As[r][col * 4] = rv;
    }
  }
}

// ---------------- fused layer: agg -> GEMM+relu+LN -> bf16 xb (round-5 proven) ----------------

__global__ __launch_bounds__(256) void k_fused(const int* __restrict__ row_start,
    const int* __restrict__ csr, const uint2* __restrict__ xb2,
    const float* __restrict__ W, const float* __restrict__ bias,
    const float* __restrict__ gamma, const float* __restrict__ beta,
    u32* __restrict__ xbout)
{
  __shared__ float As[FTILE][132];
  const int tid = threadIdx.x;
  const long row0 = (long)blockIdx.x * FTILE;

  agg_tile(row_start, csr, xb2, row0, tid, As);
  __syncthreads();

  const int cg = tid & 31;
  const int rg = tid >> 5;             // 0..7 -> 4 rows each
  const int c0 = cg * 4;
  float acc[4][4];
  {
    float4 b = *(const float4*)&bias[c0];
    #pragma unroll
    for (int r = 0; r < 4; r++){ acc[r][0]=b.x; acc[r][1]=b.y; acc[r][2]=b.z; acc[r][3]=b.w; }
  }

  for (int k = 0; k < HID; k += 4){
    float4 w0 = *(const float4*)&W[(k + 0) * HID + c0];
    float4 w1 = *(const float4*)&W[(k + 1) * HID + c0];
    float4 w2 = *(const float4*)&W[(k + 2) * HID + c0];
    float4 w3 = *(const float4*)&W[(k + 3) * HID + c0];
    #pragma unroll
    for (int r = 0; r < 4; r++){
      float4 a = *(const float4*)&As[rg * 4 + r][k];
      acc[r][0] = fmaf(a.w, w3.x, fmaf(a.z, w2.x, fmaf(a.y, w1.x, fmaf(a.x, w0.x, acc[r][0]))));
      acc[r][1] = fmaf(a.w, w3.y, fmaf(a.z, w2.y, fmaf(a.y, w1.y, fmaf(a.x, w0.y, acc[r][1]))));
      acc[r][2] = fmaf(a.w, w3.z, fmaf(a.z, w2.z, fmaf(a.y, w1.z, fmaf(a.x, w0.z, acc[r][2]))));
      acc[r][3] = fmaf(a.w, w3.w, fmaf(a.z, w2.w, fmaf(a.y, w1.w, fmaf(a.x, w0.w, acc[r][3]))));
    }
  }

  float s[4], s2[4];
  #pragma unroll
  for (int r = 0; r < 4; r++){
    float v0 = fmaxf(acc[r][0], 0.f);
    float v1 = fmaxf(acc[r][1], 0.f);
    float v2 = fmaxf(acc[r][2], 0.f);
    float v3 = fmaxf(acc[r][3], 0.f);
    acc[r][0] = v0; acc[r][1] = v1; acc[r][2] = v2; acc[r][3] = v3;
    s[r]  = (v0 + v1) + (v2 + v3);
    s2[r] = fmaf(v0, v0, fmaf(v1, v1, fmaf(v2, v2, v3 * v3)));
  }
  #pragma unroll
  for (int m = 1; m < 32; m <<= 1){
    #pragma unroll
    for (int r = 0; r < 4; r++){
      s[r]  += __shfl_xor(s[r],  m);
      s2[r] += __shfl_xor(s2[r], m);
    }
  }

  const float4 gm = *(const float4*)&gamma[c0];
  const float4 bt = *(const float4*)&beta[c0];
  #pragma unroll
  for (int r = 0; r < 4; r++){
    float mu = s[r] * (1.f / HID);
    float var = s2[r] * (1.f / HID) - mu * mu;
    float rs = 1.f / sqrtf(var + EPS);
    float4 v;
    v.x = (acc[r][0] - mu) * rs * gm.x + bt.x;
    v.y = (acc[r][1] - mu) * rs * gm.y + bt.y;
    v.z = (acc[r][2] - mu) * rs * gm.z + bt.z;
    v.w = (acc[r][3] - mu) * rs * gm.w + bt.w;
    long row = row0 + rg * 4 + r;
    uint2 p; p.x = pack2bf(v.x, v.y); p.y = pack2bf(v.z, v.w);
    *(uint2*)&xbout[(row * HID + c0) >> 1] = p;
  }
}

// ---------------- output GEMM [rows,128](bf16) @ [128,16] ----------------

__global__ __launch_bounds__(256) void k_gemm_out(const u32* __restrict__ xb,
    const float* __restrict__ Wo, const float* __restrict__ bo, float* __restrict__ out)
{
  __shared__ float As[16][132];
  __shared__ float Wl[HID * OUTF];
  const int tid = threadIdx.x;
  const long row0 = (long)blockIdx.x * 16;
  {
    // 16 rows x 16 uint4 (8 bf16 each) = 256 loads, one per thread
    int r = tid >> 4, u = tid & 15;
    uint4 v = ((const uint4*)xb)[(row0 + r) * 16 + u];
    float* d = &As[r][u * 8];
    d[0] = __uint_as_float(v.x << 16); d[1] = __uint_as_float(v.x & 0xffff0000u);
    d[2] = __uint_as_float(v.y << 16); d[3] = __uint_as_float(v.y & 0xffff0000u);
    d[4] = __uint_as_float(v.z << 16); d[5] = __uint_as_float(v.z & 0xffff0000u);
    d[6] = __uint_as_float(v.w << 16); d[7] = __uint_as_float(v.w & 0xffff0000u);
  }
  for (int i = tid; i < HID * OUTF; i += 256) Wl[i] = Wo[i];
  __syncthreads();
  int col = tid & 15, r = tid >> 4;
  float acc = bo[col];
  for (int k = 0; k < HID; k += 4){
    float4 a = *(const float4*)&As[r][k];
    acc = fmaf(a.x, Wl[(k + 0) * OUTF + col],
          fmaf(a.y, Wl[(k + 1) * OUTF + col],
          fmaf(a.z, Wl[(k + 2) * OUTF + col],
          fmaf(a.w, Wl[(k + 3) * OUTF + col], acc))));
  }
  out[(row0 + r) * OUTF + col] = acc;
}

// ---------------- launch ----------------

extern "C" void kernel_launch(void* const* d_in, const int* in_sizes, int n_in,
                              void* d_out, int out_size, void* d_ws, size_t ws_size,
                              hipStream_t stream)
{
  (void)in_sizes; (void)n_in; (void)out_size; (void)ws_size;
  const float* nodes = (const float*)d_in[0];
  const int*   src   = (const int*)d_in[1];
  const int*   dst   = (const int*)d_in[2];
  const float* W_in  = (const float*)d_in[3];
  const float* b_in  = (const float*)d_in[4];
  const float* Ws    = (const float*)d_in[5];
  const float* bs    = (const float*)d_in[6];
  const float* gam   = (const float*)d_in[7];
  const float* bet   = (const float*)d_in[8];
  const float* W_out = (const float*)d_in[9];
  const float* b_out = (const float*)d_in[10];
  float* out = (float*)d_out;

  size_t off = 0;
  auto bump = [&](size_t bytes) -> char* {
    char* p = (char*)d_ws + off;
    off = (off + bytes + 255) & ~(size_t)255;
    return p;
  };
  int* row_start     = (int*)bump((N_NODES + 1) * sizeof(int));
  int* range_cursor  = (int*)bump(NRANGES * sizeof(int));
  int* bucket_cursor = (int*)bump(NBUCKETS * sizeof(int));
  int* csr           = (int*)bump((size_t)N_EDGES * sizeof(int));
  u32* xb0           = (u32*)bump((size_t)N_NODES * HID * sizeof(unsigned short));
  u32* xb1           = (u32*)bump((size_t)N_NODES * HID * sizeof(unsigned short));
  u32* ebuf1         = (u32*)bump((size_t)NRANGES * RCAP * sizeof(u32));  // own buffer: front writes xb0 concurrently

  // ebuf2 (30.4MB) aliases xb1 (51.2MB): P3 consumes ebuf2 before layer-0 writes xb1.
  u32* ebuf2 = (u32*)xb1;

  k_initcur<<<4, 256, 0, stream>>>(range_cursor, bucket_cursor);
  k_front<<<NBATCH + N_NODES / 64, 256, 0, stream>>>(src, dst, range_cursor, ebuf1,
                                                     nodes, W_in, b_in, xb0);
  k_p2<<<NRANGES * RBLK, 256, 0, stream>>>(ebuf1, range_cursor, bucket_cursor, ebuf2);
  k_p3<<<NBUCKETS, 256, 0, stream>>>(ebuf2, bucket_cursor, csr, row_start);

  const u32* xbi = xb0; u32* xbo = xb1;
  for (int l = 0; l < LAYERS; l++){
    k_fused<<<N_NODES / FTILE, 256, 0, stream>>>(row_start, csr, (const uint2*)xbi,
                                                 Ws + (size_t)l * HID * HID, bs + l * HID,
                                                 gam + l * HID, bet + l * HID, xbo);
    const u32* tb = xbi; xbi = xbo; xbo = (u32*)tb;
  }

  k_gemm_out<<<N_NODES / 16, 256, 0, stream>>>(xbi, W_out, b_out, out);
}

// Round 10
// 1209.963 us; speedup vs baseline: 1.1075x; 1.0189x over previous
//
#include <hip/hip_runtime.h>

#define N_NODES 200000
#define N_EDGES 6400000
#define HID 128
#define OUTF 16
#define LAYERS 3
#define EPS 1e-5f

#define NRANGES 16
#define RANGE_N 12500                 // nodes per range
#define NBUCKETS 800
#define BUCKET_N 250                  // nodes per bucket
#define BATCH 5000                    // edges per sort batch
#define NBATCH (N_EDGES / BATCH)      // 1280
#define RCAP 405000                   // range segment capacity (mean 400000, sigma ~612)
#define RBLK (RCAP / BATCH)           // 81 P2 blocks per range
#define BCAP 9500                     // bucket segment capacity (mean 8000, sigma ~89)

#define FTILE 32                      // fused-layer tile rows (LDS 16.9KB -> 8 blocks/CU)

typedef unsigned int u32;

__device__ __forceinline__ unsigned short f2bf(float f){
  unsigned int u = __float_as_uint(f);
  u += 0x7fffu + ((u >> 16) & 1u);   // RNE
  return (unsigned short)(u >> 16);
}
__device__ __forceinline__ u32 pack2bf(float lo, float hi){
  return (u32)f2bf(lo) | ((u32)f2bf(hi) << 16);
}

// ---------------- cursor init ----------------

__global__ __launch_bounds__(256) void k_initcur(int* __restrict__ range_cursor,
                                                 int* __restrict__ bucket_cursor){
  int t = blockIdx.x * 256 + threadIdx.x;
  if (t < NRANGES) range_cursor[t] = t * RCAP;
  if (t < NBUCKETS) bucket_cursor[t] = t * BCAP;
}

// ---------------- FRONT: p1 (blocks 0..NBATCH-1) || gemm128 (rest) ----------------

__global__ __launch_bounds__(256) void k_front(const int* __restrict__ src, const int* __restrict__ dst,
    int* __restrict__ range_cursor, u32* __restrict__ ebuf1,
    const float* __restrict__ A, const float* __restrict__ W,
    const float* __restrict__ bias, u32* __restrict__ xbout)
{
  __shared__ __align__(16) char smraw[64 * 132 * 4];
  const int tid = threadIdx.x;

  if (blockIdx.x < NBATCH){
    // ---- P1: batch-sort edges into 16 dst ranges ----
    u32* stage = (u32*)smraw;                 // BATCH * 4 = 20000 B
    int* hist  = (int*)(smraw + 20000);       // 16
    int* hist2 = hist + 16;
    int* hbase = hist + 32;
    int* gbase = hist + 48;
    const long e0 = (long)blockIdx.x * BATCH;

    if (tid < NRANGES){ hist[tid] = 0; hist2[tid] = 0; }
    __syncthreads();
    for (int i = tid; i < BATCH; i += 256){
      int d = dst[e0 + i];
      atomicAdd(&hist[d / RANGE_N], 1);
    }
    __syncthreads();
    if (tid == 0){ int run = 0; for (int b = 0; b < NRANGES; b++){ hbase[b] = run; run += hist[b]; } }
    __syncthreads();
    if (tid < NRANGES && hist[tid] > 0) gbase[tid] = atomicAdd(&range_cursor[tid], hist[tid]);
    __syncthreads();
    for (int i = tid; i < BATCH; i += 256){
      int d = dst[e0 + i];
      int s = src[e0 + i];
      int r = d / RANGE_N;
      u32 pk = ((u32)(d - r * RANGE_N) << 18) | (u32)s;
      int p = atomicAdd(&hist2[r], 1);
      stage[hbase[r] + p] = pk;
    }
    __syncthreads();
    for (int b = 0; b < NRANGES; b++){
      int len = hist[b];
      int gb = gbase[b], hb = hbase[b];
      for (int i = tid; i < len; i += 256) ebuf1[gb + i] = stage[hb + i];
    }
    return;
  }

  // ---- input GEMM [64,128] @ [128,128] -> bf16 xb ----
  float (*As)[132] = (float (*)[132])smraw;
  const long row0 = (long)(blockIdx.x - NBATCH) * 64;

  const float4* A4 = (const float4*)(A + row0 * HID);
  for (int i = tid; i < 64 * 32; i += 256){
    int r = i >> 5, c = i & 31;
    *(float4*)&As[r][c * 4] = A4[r * 32 + c];
  }
  __syncthreads();

  const int cg = tid & 31;
  const int rg = tid >> 5;
  const int c0 = cg * 4;
  float acc[8][4];
  {
    float4 b = *(const float4*)&bias[c0];
    #pragma unroll
    for (int r = 0; r < 8; r++){ acc[r][0]=b.x; acc[r][1]=b.y; acc[r][2]=b.z; acc[r][3]=b.w; }
  }

  for (int k = 0; k < HID; k += 4){
    float4 w0 = *(const float4*)&W[(k + 0) * HID + c0];
    float4 w1 = *(const float4*)&W[(k + 1) * HID + c0];
    float4 w2 = *(const float4*)&W[(k + 2) * HID + c0];
    float4 w3 = *(const float4*)&W[(k + 3) * HID + c0];
    #pragma unroll
    for (int r = 0; r < 8; r++){
      float4 a = *(const float4*)&As[rg * 8 + r][k];
      acc[r][0] = fmaf(a.w, w3.x, fmaf(a.z, w2.x, fmaf(a.y, w1.x, fmaf(a.x, w0.x, acc[r][0]))));
      acc[r][1] = fmaf(a.w, w3.y, fmaf(a.z, w2.y, fmaf(a.y, w1.y, fmaf(a.x, w0.y, acc[r][1]))));
      acc[r][2] = fmaf(a.w, w3.z, fmaf(a.z, w2.z, fmaf(a.y, w1.z, fmaf(a.x, w0.z, acc[r][2]))));
      acc[r][3] = fmaf(a.w, w3.w, fmaf(a.z, w2.w, fmaf(a.y, w1.w, fmaf(a.x, w0.w, acc[r][3]))));
    }
  }

  #pragma unroll
  for (int r = 0; r < 8; r++){
    long row = row0 + rg * 8 + r;
    uint2 p; p.x = pack2bf(acc[r][0], acc[r][1]); p.y = pack2bf(acc[r][2], acc[r][3]);
    *(uint2*)&xbout[(row * HID + c0) >> 1] = p;
  }
}

// ---------------- P2: per-range batch-sort into 50 buckets (full-line flushes) ----------------

__global__ __launch_bounds__(256) void k_p2(const u32* __restrict__ ebuf1, const int* __restrict__ range_cursor,
                                            int* __restrict__ bucket_cursor, u32* __restrict__ ebuf2){
  __shared__ u32 stage[BATCH];
  __shared__ int hist[50], hist2[50], hbase[50], gbase[50];
  const int tid = threadIdx.x;
  const int r = blockIdx.x / RBLK;
  const int chunk = blockIdx.x % RBLK;
  const int rlen = range_cursor[r] - r * RCAP;
  const int i0 = chunk * BATCH;
  const int len = min(BATCH, rlen - i0);
  if (len <= 0) return;
  const u32* seg = ebuf1 + (long)r * RCAP + i0;

  if (tid < 50){ hist[tid] = 0; hist2[tid] = 0; }
  __syncthreads();
  for (int i = tid; i < len; i += 256){
    int dl = (int)(seg[i] >> 18);
    atomicAdd(&hist[dl / BUCKET_N], 1);
  }
  __syncthreads();
  if (tid == 0){ int run = 0; for (int b = 0; b < 50; b++){ hbase[b] = run; run += hist[b]; } }
  __syncthreads();
  if (tid < 50 && hist[tid] > 0) gbase[tid] = atomicAdd(&bucket_cursor[r * 50 + tid], hist[tid]);
  __syncthreads();
  for (int i = tid; i < len; i += 256){
    u32 pk = seg[i];
    int b = (int)(pk >> 18) / BUCKET_N;
    int p = atomicAdd(&hist2[b], 1);
    stage[hbase[b] + p] = pk;
  }
  __syncthreads();
  for (int b = 0; b < 50; b++){
    int l = hist[b];
    if (l == 0) continue;
    int gb = gbase[b], hb = hbase[b];
    for (int i = tid; i < l; i += 256) ebuf2[gb + i] = stage[hb + i];
  }
}

// ---------------- P3: per-bucket LDS scatter; computes own base (scanb folded in) ----------------

__global__ __launch_bounds__(256) void k_p3(const u32* __restrict__ ebuf2, const int* __restrict__ bucket_cursor,
                                            int* __restrict__ csr, int* __restrict__ row_start){
  __shared__ int stage[BCAP];
  __shared__ int hist[BUCKET_N], sbase[BUCKET_N], cur[BUCKET_N];
  __shared__ int q[256];
  __shared__ int base_s;
  const int tid = threadIdx.x;
  const int b = blockIdx.x;
  const int n0 = b * BUCKET_N;
  const int dl0 = (b % 50) * BUCKET_N;
  const int len = min(bucket_cursor[b] - b * BCAP, BCAP);
  const u32* seg = ebuf2 + (long)b * BCAP;

  // ---- bucket_base via in-block reduction over buckets < b (800 L2-hot ints) ----
  {
    int partial = 0;
    for (int i = tid; i < b; i += 256) partial += bucket_cursor[i] - i * BCAP;
    q[tid] = partial; __syncthreads();
    for (int off = 128; off > 0; off >>= 1){
      if (tid < off) q[tid] += q[tid + off];
      __syncthreads();
    }
    if (tid == 0) base_s = q[0];
  }

  if (tid < BUCKET_N){ hist[tid] = 0; cur[tid] = 0; }
  __syncthreads();
  const int base = base_s;
  for (int i = tid; i < len; i += 256){
    int local = (int)(seg[i] >> 18) - dl0;
    local = min(max(local, 0), BUCKET_N - 1);   // safety clamp (statistically unreachable)
    atomicAdd(&hist[local], 1);
  }
  __syncthreads();
  {
    int v = (tid < BUCKET_N) ? hist[tid] : 0;
    q[tid] = v; __syncthreads();
    for (int off = 1; off < 256; off <<= 1){
      int t = (tid >= off) ? q[tid - off] : 0;
      __syncthreads();
      q[tid] += t;
      __syncthreads();
    }
    if (tid < BUCKET_N) sbase[tid] = q[tid] - v;
  }
  __syncthreads();
  for (int i = tid; i < len; i += 256){
    u32 pk = seg[i];
    int local = (int)(pk >> 18) - dl0;
    local = min(max(local, 0), BUCKET_N - 1);
    int pos = atomicAdd(&cur[local], 1);
    stage[sbase[local] + pos] = (int)(pk & 0x3FFFFu);
  }
  __syncthreads();
  for (int i = tid; i < len; i += 256) csr[base + i] = stage[i];
  if (tid < BUCKET_N) row_start[n0 + tid] = base + sbase[tid];
  if (b == NBUCKETS - 1 && tid == 0) row_start[N_NODES] = base + len;
}

// ---------------- gather phase (round-5 proven body) ----------------
// Wave wv writes ONLY As rows 8wv..8wv+7 (wave-private LDS ownership).

__device__ __forceinline__ void agg_tile(const int* __restrict__ row_start,
    const int* __restrict__ csr, const uint2* __restrict__ xb2,
    long row0, int tid, float (*As)[132])
{
  const int wv = tid >> 6;
  const int lane = tid & 63;
  const int half = lane >> 5, col = lane & 31;
  const uint2* xbc = xb2 + col;

  for (int i = 0; i < FTILE / 4; i++){
    const int r = wv * (FTILE / 4) + i;
    const int node = (int)row0 + r;
    const int s0 = row_start[node], s1 = row_start[node + 1];

    float4 xs = {0.f, 0.f, 0.f, 0.f};
    if (half == 0){
      uint2 sv = xb2[(long)node * 32 + col];
      xs.x = __uint_as_float(sv.x << 16);
      xs.y = __uint_as_float(sv.x & 0xffff0000u);
      xs.z = __uint_as_float(sv.y << 16);
      xs.w = __uint_as_float(sv.y & 0xffff0000u);
    }

    float a0 = 0.f, a1 = 0.f, a2 = 0.f, a3 = 0.f;
    int base = s0;
    int idx[8];
    if (base + 16 <= s1){
      #pragma unroll
      for (int j = 0; j < 8; j++) idx[j] = csr[base + 2*j + half];
    }
    while (base + 16 <= s1){
      uint2 p[8];
      #pragma unroll
      for (int j = 0; j < 8; j++) p[j] = xbc[(long)idx[j] * 32];
      base += 16;
      if (base + 16 <= s1){
        #pragma unroll
        for (int j = 0; j < 8; j++) idx[j] = csr[base + 2*j + half];
      }
      #pragma unroll
      for (int j = 0; j < 8; j++){
        a0 += __uint_as_float(p[j].x << 16);
        a1 += __uint_as_float(p[j].x & 0xffff0000u);
        a2 += __uint_as_float(p[j].y << 16);
        a3 += __uint_as_float(p[j].y & 0xffff0000u);
      }
    }
    if (base < s1){
      const int s1m1 = s1 - 1;
      int ti[8];
      #pragma unroll
      for (int j = 0; j < 8; j++) ti[j] = csr[min(base + 2*j + half, s1m1)];
      uint2 p[8];
      #pragma unroll
      for (int j = 0; j < 8; j++) p[j] = xbc[(long)ti[j] * 32];
      #pragma unroll
      for (int j = 0; j < 8; j++){
        bool act = (base + 2*j + half) < s1;
        float v0 = __uint_as_float(p[j].x << 16);
        float v1 = __uint_as_float(p[j].x & 0xffff0000u);
        float v2 = __uint_as_float(p[j].y << 16);
        float v3 = __uint_as_float(p[j].y & 0xffff0000u);
        a0 += act ? v0 : 0.f;
        a1 += act ? v1 : 0.f;
        a2 += act ? v2 : 0.f;
        a3 += act ? v3 : 0.f;
      }
    }

    a0 += __shfl_down(a0, 32);
    a1 += __shfl_down(a1, 32);
    a2 += __shfl_down(a2, 32);
    a3 += __shfl_down(a3, 32);

    if (half == 0){
      float inv = 1.f / (float)(s1 - s0 + 1);
      float4 rv;
      rv.x = (a0 + xs.x) * inv;
      rv.y = (a1 + xs.y) * inv;
      rv.z = (a2 + xs.z) * inv;
      rv.w = (a3 + xs.w) * inv;
      *(float4*)&As[r][col * 4] = rv;
    }
  }
}

// ---------------- fused layer: agg -> GEMM+relu+LN -> bf16 xb ----------------
// NO barrier between phase A and B: wave wv's phase B (rg = 2wv, 2wv+1) reads
// exactly As rows 8wv..8wv+7, which wave wv itself wrote in phase A. LDS
// ownership is wave-private; in-wave ds ordering is guaranteed by lgkmcnt.
// Waves therefore flow A->B independently, staggering naturally (degree
// jitter) so some waves always gather while others run FMAs (de-convoy).

__global__ __launch_bounds__(256) void k_fused(const int* __restrict__ row_start,
    const int* __restrict__ csr, const uint2* __restrict__ xb2,
    const float* __restrict__ W, const float* __restrict__ bias,
    const float* __restrict__ gamma, const float* __restrict__ beta,
    u32* __restrict__ xbout)
{
  __shared__ float As[FTILE][132];
  const int tid = threadIdx.x;
  const long row0 = (long)blockIdx.x * FTILE;

  agg_tile(row_start, csr, xb2, row0, tid, As);
  // (no __syncthreads: see header comment)

  const int cg = tid & 31;
  const int rg = tid >> 5;             // 0..7 -> 4 rows each; wave-private rows
  const int c0 = cg * 4;
  float acc[4][4];
  {
    float4 b = *(const float4*)&bias[c0];
    #pragma unroll
    for (int r = 0; r < 4; r++){ acc[r][0]=b.x; acc[r][1]=b.y; acc[r][2]=b.z; acc[r][3]=b.w; }
  }

  for (int k = 0; k < HID; k += 4){
    float4 w0 = *(const float4*)&W[(k + 0) * HID + c0];
    float4 w1 = *(const float4*)&W[(k + 1) * HID + c0];
    float4 w2 = *(const float4*)&W[(k + 2) * HID + c0];
    float4 w3 = *(const float4*)&W[(k + 3) * HID + c0];
    #pragma unroll
    for (int r = 0; r < 4; r++){
      float4 a = *(const float4*)&As[rg * 4 + r][k];
      acc[r][0] = fmaf(a.w, w3.x, fmaf(a.z, w2.x, fmaf(a.y, w1.x, fmaf(a.x, w0.x, acc[r][0]))));
      acc[r][1] = fmaf(a.w, w3.y, fmaf(a.z, w2.y, fmaf(a.y, w1.y, fmaf(a.x, w0.y, acc[r][1]))));
      acc[r][2] = fmaf(a.w, w3.z, fmaf(a.z, w2.z, fmaf(a.y, w1.z, fmaf(a.x, w0.z, acc[r][2]))));
      acc[r][3] = fmaf(a.w, w3.w, fmaf(a.z, w2.w, fmaf(a.y, w1.w, fmaf(a.x, w0.w, acc[r][3]))));
    }
  }

  float s[4], s2[4];
  #pragma unroll
  for (int r = 0; r < 4; r++){
    float v0 = fmaxf(acc[r][0], 0.f);
    float v1 = fmaxf(acc[r][1], 0.f);
    float v2 = fmaxf(acc[r][2], 0.f);
    float v3 = fmaxf(acc[r][3], 0.f);
    acc[r][0] = v0; acc[r][1] = v1; acc[r][2] = v2; acc[r][3] = v3;
    s[r]  = (v0 + v1) + (v2 + v3);
    s2[r] = fmaf(v0, v0, fmaf(v1, v1, fmaf(v2, v2, v3 * v3)));
  }
  #pragma unroll
  for (int m = 1; m < 32; m <<= 1){
    #pragma unroll
    for (int r = 0; r < 4; r++){
      s[r]  += __shfl_xor(s[r],  m);
      s2[r] += __shfl_xor(s2[r], m);
    }
  }

  const float4 gm = *(const float4*)&gamma[c0];
  const float4 bt = *(const float4*)&beta[c0];
  #pragma unroll
  for (int r = 0; r < 4; r++){
    float mu = s[r] * (1.f / HID);
    float var = s2[r] * (1.f / HID) - mu * mu;
    float rs = 1.f / sqrtf(var + EPS);
    float4 v;
    v.x = (acc[r][0] - mu) * rs * gm.x + bt.x;
    v.y = (acc[r][1] - mu) * rs * gm.y + bt.y;
    v.z = (acc[r][2] - mu) * rs * gm.z + bt.z;
    v.w = (acc[r][3] - mu) * rs * gm.w + bt.w;
    long row = row0 + rg * 4 + r;
    uint2 p; p.x = pack2bf(v.x, v.y); p.y = pack2bf(v.z, v.w);
    *(uint2*)&xbout[(row * HID + c0) >> 1] = p;
  }
}

// ---------------- output GEMM [rows,128](bf16) @ [128,16] ----------------

__global__ __launch_bounds__(256) void k_gemm_out(const u32* __restrict__ xb,
    const float* __restrict__ Wo, const float* __restrict__ bo, float* __restrict__ out)
{
  __shared__ float As[16][132];
  __shared__ float Wl[HID * OUTF];
  const int tid = threadIdx.x;
  const long row0 = (long)blockIdx.x * 16;
  {
    // 16 rows x 16 uint4 (8 bf16 each) = 256 loads, one per thread
    int r = tid >> 4, u = tid & 15;
    uint4 v = ((const uint4*)xb)[(row0 + r) * 16 + u];
    float* d = &As[r][u * 8];
    d[0] = __uint_as_float(v.x << 16); d[1] = __uint_as_float(v.x & 0xffff0000u);
    d[2] = __uint_as_float(v.y << 16); d[3] = __uint_as_float(v.y & 0xffff0000u);
    d[4] = __uint_as_float(v.z << 16); d[5] = __uint_as_float(v.z & 0xffff0000u);
    d[6] = __uint_as_float(v.w << 16); d[7] = __uint_as_float(v.w & 0xffff0000u);
  }
  for (int i = tid; i < HID * OUTF; i += 256) Wl[i] = Wo[i];
  __syncthreads();
  int col = tid & 15, r = tid >> 4;
  float acc = bo[col];
  for (int k = 0; k < HID; k += 4){
    float4 a = *(const float4*)&As[r][k];
    acc = fmaf(a.x, Wl[(k + 0) * OUTF + col],
          fmaf(a.y, Wl[(k + 1) * OUTF + col],
          fmaf(a.z, Wl[(k + 2) * OUTF + col],
          fmaf(a.w, Wl[(k + 3) * OUTF + col], acc))));
  }
  out[(row0 + r) * OUTF + col] = acc;
}

// ---------------- launch ----------------

extern "C" void kernel_launch(void* const* d_in, const int* in_sizes, int n_in,
                              void* d_out, int out_size, void* d_ws, size_t ws_size,
                              hipStream_t stream)
{
  (void)in_sizes; (void)n_in; (void)out_size; (void)ws_size;
  const float* nodes = (const float*)d_in[0];
  const int*   src   = (const int*)d_in[1];
  const int*   dst   = (const int*)d_in[2];
  const float* W_in  = (const float*)d_in[3];
  const float* b_in  = (const float*)d_in[4];
  const float* Ws    = (const float*)d_in[5];
  const float* bs    = (const float*)d_in[6];
  const float* gam   = (const float*)d_in[7];
  const float* bet   = (const float*)d_in[8];
  const float* W_out = (const float*)d_in[9];
  const float* b_out = (const float*)d_in[10];
  float* out = (float*)d_out;

  size_t off = 0;
  auto bump = [&](size_t bytes) -> char* {
    char* p = (char*)d_ws + off;
    off = (off + bytes + 255) & ~(size_t)255;
    return p;
  };
  int* row_start     = (int*)bump((N_NODES + 1) * sizeof(int));
  int* range_cursor  = (int*)bump(NRANGES * sizeof(int));
  int* bucket_cursor = (int*)bump(NBUCKETS * sizeof(int));
  int* csr           = (int*)bump((size_t)N_EDGES * sizeof(int));
  u32* xb0           = (u32*)bump((size_t)N_NODES * HID * sizeof(unsigned short));
  u32* xb1           = (u32*)bump((size_t)N_NODES * HID * sizeof(unsigned short));
  u32* ebuf1         = (u32*)bump((size_t)NRANGES * RCAP * sizeof(u32));  // own buffer: front writes xb0 concurrently

  // ebuf2 (30.4MB) aliases xb1 (51.2MB): P3 consumes ebuf2 before layer-0 writes xb1.
  u32* ebuf2 = (u32*)xb1;

  k_initcur<<<4, 256, 0, stream>>>(range_cursor, bucket_cursor);
  k_front<<<NBATCH + N_NODES / 64, 256, 0, stream>>>(src, dst, range_cursor, ebuf1,
                                                     nodes, W_in, b_in, xb0);
  k_p2<<<NRANGES * RBLK, 256, 0, stream>>>(ebuf1, range_cursor, bucket_cursor, ebuf2);
  k_p3<<<NBUCKETS, 256, 0, stream>>>(ebuf2, bucket_cursor, csr, row_start);

  const u32* xbi = xb0; u32* xbo = xb1;
  for (int l = 0; l < LAYERS; l++){
    k_fused<<<N_NODES / FTILE, 256, 0, stream>>>(row_start, csr, (const uint2*)xbi,
                                                 Ws + (size_t)l * HID * HID, bs + l * HID,
                                                 gam + l * HID, bet + l * HID, xbo);
    const u32* tb = xbi; xbi = xbo; xbo = (u32*)tb;
  }

  k_gemm_out<<<N_NODES / 16, 256, 0, stream>>>(xbi, W_out, b_out, out);
}